// Round 15
// baseline (829.456 us; speedup 1.0000x reference)
//
#include <hip/hip_runtime.h>
#include <hip/hip_bf16.h>
#include <stdint.h>

// ---------------------------------------------------------------------------
// RNN_79164837199890: 2-layer LSTM (B=128,T=512,H=128) + policy/value heads.
// R15: scan/conv/heads-compute = R7 verbatim (controls). Changes:
//  - k_gemm2: 512 WGs x 512 thr; full A tile (128x384 bf16, 96KB) staged to
//    LDS ONCE per t-tile, B streamed via 2x16KB dbuf over 4 N-tiles x 6 ks.
//    States HBM traffic 360MB -> 90MB (was re-read 4x by N-tiles).
//  - k_final folded into k_heads (last-WG ticket on accum[4]); one fewer
//    launch. conv zeroes 8 accum slots now.
// ---------------------------------------------------------------------------

typedef short v8s __attribute__((ext_vector_type(8)));   // 8 x bf16 fragment
typedef float v4f __attribute__((ext_vector_type(4)));   // MFMA accumulator
typedef int   v8i __attribute__((ext_vector_type(8)));   // 32 x fp8 fragment
typedef float f4u __attribute__((ext_vector_type(4), aligned(4)));  // unaligned-ok

#define MFMA_B16(a,b,c) __builtin_amdgcn_mfma_f32_16x16x32_bf16((a),(b),(c),0,0,0)
#define MFMA_MX(a,b,c) \
  __builtin_amdgcn_mfma_scale_f32_16x16x128_f8f6f4((a),(b),(c),0,0,0,0x7F7F7F7F,0,0x7F7F7F7F)

#define NT     512
#define FIN    361
#define KP0    384
#define NPC    362
#define NPP    368
#define AG __HIP_MEMORY_SCOPE_AGENT

// workspace offsets (bytes)
#define OFF_Z    ((size_t)0)          // 65536*512*2 = 67108864 (z0x, gate-packed)
#define OFF_H1   ((size_t)83886080)   // 65536*128*2 = 16777216
#define OFF_W0XT ((size_t)100663296)  // 512*384*2 = 393216
#define OFF_WPT  ((size_t)101187584)  // 368*128*2 = 94208
#define OFF_B0P  ((size_t)101281792)  // 512*4
#define OFF_BPP  ((size_t)101285888)  // 368*4
#define OFF_ACC  ((size_t)101287936)  // 8 floats (4 sums + ticket + pad)

static __device__ __forceinline__ short f2b(float f) {
  __hip_bfloat16 h = __float2bfloat16(f);
  union { __hip_bfloat16 h; short s; } cv; cv.h = h; return cv.s;
}
static __device__ __forceinline__ float b2f(unsigned int lo16) {
  union { unsigned u; float f; } cv; cv.u = lo16 << 16; return cv.f;
}
// f32 -> OCP e4m3fn with RNE (one-time weight packs)
static __device__ __forceinline__ unsigned f2e4m3(float f) {
  union { float f; unsigned u; } cv; cv.f = f;
  unsigned s = (cv.u >> 31) << 7;
  float a = fabsf(f);
  a = fminf(a, 448.f);
  unsigned code;
  if (a >= 0.015625f) {
    union { float f; unsigned u; } m; m.f = a;
    unsigned u = m.u + 0x7FFFF + ((m.u >> 20) & 1);
    code = (u >> 20) - 960;
    if (code > 126u) code = 126u;
  } else {
    code = (unsigned)rintf(a * 512.f);
  }
  return s | code;
}
// per-step fp8 encode (R7 path)
static __device__ __forceinline__ unsigned f2e4m3_fast(float f) {
#if __has_builtin(__builtin_amdgcn_cvt_pk_fp8_f32)
  return (unsigned)__builtin_amdgcn_cvt_pk_fp8_f32(f, f, 0, false) & 0xffu;
#else
  return f2e4m3(f);
#endif
}

// Raw barrier with LDS-only drain (global stores/loads keep floating).
static __device__ __forceinline__ void sync_lds() {
  __builtin_amdgcn_sched_barrier(0);
  asm volatile("s_waitcnt lgkmcnt(0)" ::: "memory");
  __builtin_amdgcn_s_barrier();
  __builtin_amdgcn_sched_barrier(0);
}

// --------------------------------------------------------------------------
// K0: weight conversion (R7 exact; accum zeroing extended to 8).
// --------------------------------------------------------------------------
__global__ __launch_bounds__(256) void k_conv_weights(
    const float* __restrict__ W0, const float* __restrict__ b0,
    const float* __restrict__ Wp, const float* __restrict__ bp,
    char* __restrict__ ws) {
  int idx = blockIdx.x * 256 + threadIdx.x;
  __hip_bfloat16* W0xT = (__hip_bfloat16*)(ws + OFF_W0XT);
  __hip_bfloat16* WpT  = (__hip_bfloat16*)(ws + OFF_WPT);
  float* b0p = (float*)(ws + OFF_B0P);
  float* bpp = (float*)(ws + OFF_BPP);
  float* acc = (float*)(ws + OFF_ACC);

  if (idx < 196608) {                       // W0xT [512 cols'][384 k]
    int np = idx / 384, k = idx - np * 384;
    int n = (np >> 2) + 128 * (np & 3);
    float v = (k < FIN) ? W0[(size_t)k * 512 + n] : 0.f;
    W0xT[idx] = __float2bfloat16(v);
    return;
  }
  idx -= 196608;
  if (idx < 47104) {                        // WpT [368 p][128 k]
    int p = idx >> 7, k = idx & 127;
    WpT[idx] = __float2bfloat16(p < NPC ? Wp[(size_t)k * NPC + p] : 0.f);
    return;
  }
  idx -= 47104;
  if (idx < 512) {                          // b0p packed, +1.0 on forget gate
    int n = (idx >> 2) + 128 * (idx & 3);
    b0p[idx] = b0[n] + (((idx & 3) == 1) ? 1.0f : 0.0f);
    return;
  }
  idx -= 512;
  if (idx < NPP) { bpp[idx] = (idx < NPC) ? bp[idx] : -1e30f; return; }
  idx -= NPP;
  if (idx < 8) { acc[idx] = 0.f; return; }
}

// --------------------------------------------------------------------------
// K1: z0x GEMM, states read ONCE. Grid 512 (one WG per t), 512 thr (8 waves).
// LDS: A full [128 rows][768B] swizzled @0 (96KB); B dbuf 2x16KB @98304.
// A swizzle: addr = row*768 + (byo&~127) + ((byo&127) ^ ((((byo>>7)^row)&7)<<4)).
// Wave wv owns rows wv*16..+15; per (by,ks): 2 kk x 8 nt MFMA.
// --------------------------------------------------------------------------
__global__ __launch_bounds__(512) void k_gemm2(
    const float* __restrict__ states, const __hip_bfloat16* __restrict__ BT,
    const float* __restrict__ bias, __hip_bfloat16* __restrict__ C) {
  __shared__ char sm[131072];
  const int tid = threadIdx.x;
  const int l = tid & 63, wv = tid >> 6;
  const int c = l & 15, lg = l >> 4;
  const int t_ = blockIdx.x;

  auto SWA = [](int row, int byo) {
    return (byo & ~127) + ((byo & 127) ^ ((((byo >> 7) ^ row) & 7) << 4));
  };

  // ---- stage full A tile (once): thread = (row tid>>2, quarter tid&3) ----
  {
    const int arow = tid >> 2, q = tid & 3;
    const float* src = states + ((size_t)arow * NT + t_) * FIN;
#pragma unroll
    for (int j = 0; j < 12; j++) {
      int kb = q * 96 + j * 8;
      v8s w;
      if (kb + 8 <= FIN) {
        f4u a0 = *(const f4u*)(src + kb);
        f4u a1 = *(const f4u*)(src + kb + 4);
#pragma unroll
        for (int u = 0; u < 4; u++) { w[u] = f2b(a0[u]); w[4 + u] = f2b(a1[u]); }
      } else {
#pragma unroll
        for (int u = 0; u < 8; u++) {
          int kf = kb + u;
          w[u] = f2b((kf < FIN) ? src[kf] : 0.f);
        }
      }
      *(v8s*)(sm + arow * 768 + SWA(arow, kb * 2)) = w;
    }
  }

  // ---- B streaming (2 uint4 per thread per slice) ----
  uint4 rb[2];
  auto LD_B = [&](int by, int ks) {
#pragma unroll
    for (int i = 0; i < 2; i++) {
      int idx = i * 8192 + tid * 16;
      int row = idx >> 7, colb = idx & 127;
      rb[i] = *(const uint4*)((const char*)BT +
          ((size_t)(by * 128 + row) * KP0 + ks * 64) * 2 + colb);
    }
  };
  auto ST_B = [&](int bsel) {
#pragma unroll
    for (int i = 0; i < 2; i++) {
      int idx = i * 8192 + tid * 16;
      int row = idx >> 7, colb = idx & 127;
      *(uint4*)(sm + 98304 + bsel * 16384 + row * 128 + (colb ^ ((row & 7) << 4))) = rb[i];
    }
  };

  LD_B(0, 0); ST_B(0);
  __syncthreads();

  int st = 0;
  for (int by = 0; by < 4; by++) {
    v4f acc[8];
#pragma unroll
    for (int nt = 0; nt < 8; nt++) acc[nt] = (v4f){0.f, 0.f, 0.f, 0.f};
    for (int ks = 0; ks < 6; ks++, st++) {
      int byn = by, ksn = ks + 1;
      if (ksn == 6) { ksn = 0; byn = by + 1; }
      if (st + 1 < 24) LD_B(byn, ksn);
      const int bsel = st & 1;
#pragma unroll
      for (int kk = 0; kk < 2; kk++) {
        const int row = wv * 16 + c;
        v8s af = *(v8s*)(sm + row * 768 + SWA(row, ks * 128 + kk * 64 + lg * 16));
        const int bir = kk * 64 + lg * 16;
#pragma unroll
        for (int nt = 0; nt < 8; nt++) {
          int n = nt * 16 + c;
          v8s bf = *(v8s*)(sm + 98304 + bsel * 16384 + n * 128 + (bir ^ ((n & 7) << 4)));
          acc[nt] = MFMA_B16(af, bf, acc[nt]);
        }
      }
      if (st + 1 < 24) ST_B((st + 1) & 1);
      __syncthreads();
    }
#pragma unroll
    for (int nt = 0; nt < 8; nt++) {
      int colp = by * 128 + nt * 16 + c;
      float bs = bias[colp];
#pragma unroll
      for (int j = 0; j < 4; j++) {
        int row = t_ * 128 + wv * 16 + lg * 4 + j;
        C[(size_t)row * 512 + colp] = __float2bfloat16(acc[nt][j] + bs);
      }
    }
  }
}

// --------------------------------------------------------------------------
// K2: merged 2-layer scan (R7 VERBATIM). 32 WGs x 16 waves. role = wv>>3.
// --------------------------------------------------------------------------
__global__ __launch_bounds__(1024, 4) void k_scan12(
    const __hip_bfloat16* __restrict__ Z, const float* __restrict__ W0f,
    const float* __restrict__ W1f, const float* __restrict__ b1,
    __hip_bfloat16* __restrict__ h1out) {
  __shared__ char sm[8192];
  const int tid = threadIdx.x;
  const int l = tid & 63, wv = tid >> 6;
  const int c = l & 15, lg = l >> 4;
  const int role = wv >> 3, rw = wv & 7;
  const int B0 = blockIdx.x * 4;
  const int m_ = 16 * rw + c;
  const int row = 4 * lg;
  const int wf8 = row * 128 + (((m_ >> 3) ^ row) << 3) + (m_ & 7);

  for (int e = tid * 4; e < 8192; e += 1024 * 4) *(int*)(sm + e) = 0;

  auto AFRAG = [&](int base) -> v8i {
    union { unsigned long long q[4]; v8i v; } u;
#pragma unroll
    for (int t = 0; t < 4; t++)
      u.q[t] = *(const unsigned long long*)(
          sm + base + c * 128 + ((((lg * 4 + t) ^ c) & 15) << 3));
    return u.v;
  };

  if (role == 0) {
    // ================= L0 =================
    v8i breg[4];                             // fp8 W0h B-frags
#pragma unroll
    for (int g = 0; g < 4; g++) {
      int n = g * 128 + m_;
      union { unsigned long long q[4]; v8i v; } u;
#pragma unroll
      for (int t = 0; t < 4; t++) {
        unsigned long long w = 0ull;
#pragma unroll
        for (int j = 0; j < 8; j++) {
          int k = lg * 32 + t * 8 + j;
          w |= (unsigned long long)f2e4m3(W0f[(size_t)(FIN + k) * 512 + n]) << (8 * j);
        }
        u.q[t] = w;
      }
      breg[g] = u.v;
    }

    uint2 zA, zB, zC;
    auto ZLD = [&](int t) -> uint2 {
      return *(const uint2*)(Z + ((size_t)t * 128 + B0 + lg) * 512 + m_ * 4);
    };
    zA = ZLD(0); zB = ZLD(1);
    float cst = 0.f;
    __syncthreads();

    for (int s = 0; s < NT; s++) {
      v8i av = AFRAG(((s + 1) & 1) * 2048);  // h0(s-1) fp8
      v4f acc[4];
#pragma unroll
      for (int g = 0; g < 4; g++) acc[g] = (v4f){0.f, 0.f, 0.f, 0.f};
#pragma unroll
      for (int g = 0; g < 4; g++) acc[g] = MFMA_MX(av, breg[g], acc[g]);
      if (s + 2 < NT) zC = ZLD(s + 2);

      float xi = acc[0][0] + b2f(zA.x & 0xffffu);
      float xf = acc[1][0] + b2f(zA.x >> 16);          // +1.0 folded into b0p
      float xg = acc[2][0] + b2f(zA.y & 0xffffu);
      float xo = acc[3][0] + b2f(zA.y >> 16);
      float ei = __expf(-xi);
      float ef = __expf(-xf);
      float eg = __expf(2.f * xg);
      float eo = __expf(-xo);
      float cn = cst * __builtin_amdgcn_rcpf(1.f + ef)
               + (eg - 1.f) * __builtin_amdgcn_rcpf((1.f + ei) * (eg + 1.f));
      cst = cn;
      float ec = __expf(2.f * cn);
      float hv = (ec - 1.f) * __builtin_amdgcn_rcpf((1.f + eo) * (ec + 1.f));
      *(unsigned char*)(sm + (s & 1) * 2048 + wf8) = (unsigned char)f2e4m3_fast(hv);
      zA = zB; zB = zC;
      sync_lds();
    }
    sync_lds();                              // L1 tail step
  } else {
    // ================= L1 (one step behind) =================
    v8i bregH[4], bregX[4];                  // fp8 B-frags
#pragma unroll
    for (int g = 0; g < 4; g++) {
      int n = g * 128 + m_;
      union { unsigned long long q[4]; v8i v; } uh, ux;
#pragma unroll
      for (int t = 0; t < 4; t++) {
        unsigned long long wh = 0ull, wx = 0ull;
#pragma unroll
        for (int j = 0; j < 8; j++) {
          int k = lg * 32 + t * 8 + j;
          wh |= (unsigned long long)f2e4m3(W1f[(size_t)(128 + k) * 512 + n]) << (8 * j);
          wx |= (unsigned long long)f2e4m3(W1f[(size_t)k * 512 + n]) << (8 * j);
        }
        uh.q[t] = wh; ux.q[t] = wx;
      }
      bregH[g] = uh.v; bregX[g] = ux.v;
    }
    float bq[4];
#pragma unroll
    for (int g = 0; g < 4; g++)
      bq[g] = b1[g * 128 + m_] + ((g == 1) ? 1.0f : 0.0f);
    float cst = 0.f;
    __syncthreads();
    sync_lds();                              // skip s=0 (idle)

    for (int s = 1; s <= NT; s++) {
      v8i ah = AFRAG(4096 + (s & 1) * 2048); // h1(s-2) fp8
      v8i ax = AFRAG(((s + 1) & 1) * 2048);  // h0(s-1) fp8
      v4f acc[4];
#pragma unroll
      for (int g = 0; g < 4; g++) acc[g] = (v4f){bq[g], bq[g], bq[g], bq[g]};
#pragma unroll
      for (int g = 0; g < 4; g++) acc[g] = MFMA_MX(ah, bregH[g], acc[g]);
#pragma unroll
      for (int g = 0; g < 4; g++) acc[g] = MFMA_MX(ax, bregX[g], acc[g]);

      float xi = acc[0][0], xf = acc[1][0], xg = acc[2][0], xo = acc[3][0];
      float ei = __expf(-xi);
      float ef = __expf(-xf);
      float eg = __expf(2.f * xg);
      float eo = __expf(-xo);
      float cn = cst * __builtin_amdgcn_rcpf(1.f + ef)
               + (eg - 1.f) * __builtin_amdgcn_rcpf((1.f + ei) * (eg + 1.f));
      cst = cn;
      float ec = __expf(2.f * cn);
      float hv = (ec - 1.f) * __builtin_amdgcn_rcpf((1.f + eo) * (ec + 1.f));
      *(unsigned char*)(sm + 4096 + ((s + 1) & 1) * 2048 + wf8) =
          (unsigned char)f2e4m3_fast(hv);
      union { short s; __hip_bfloat16 h; } cv; cv.s = f2b(hv);
      h1out[((size_t)(s - 1) * 128 + B0 + lg) * 128 + m_] = cv.h;
      sync_lds();
    }
  }
}

// --------------------------------------------------------------------------
// K5: heads (R7 compute) + fused finalization via last-WG ticket.
// --------------------------------------------------------------------------
__global__ __launch_bounds__(256) void k_heads(
    const __hip_bfloat16* __restrict__ Hh, const __hip_bfloat16* __restrict__ WpT,
    const float* __restrict__ bpp, const float* __restrict__ Wv,
    const float* __restrict__ bv, const int* __restrict__ moves,
    const float* __restrict__ values, float* __restrict__ accum,
    float* __restrict__ out) {
  __shared__ char sm[110592];                // A 16KB @0, B 94208B @16384
  const int tid = threadIdx.x;
  const int l = tid & 63, wm = tid >> 6;
  const int c = l & 15, lg = l >> 4;
  const int r0 = blockIdx.x * 64;

#pragma unroll
  for (int i = 0; i < 4; i++) {
    int idx = i * 4096 + tid * 16;
    int row = idx >> 8, colb = idx & 255;
    uint4 v = *(const uint4*)((const char*)Hh + (size_t)r0 * 256 + idx);
    *(uint4*)(sm + row * 256 + (colb ^ ((row & 7) << 4))) = v;
  }
#pragma unroll
  for (int i = 0; i < 23; i++) {
    int idx = i * 4096 + tid * 16;
    int row = idx >> 8, colb = idx & 255;
    uint4 v = *(const uint4*)((const char*)WpT + idx);
    *(uint4*)(sm + 16384 + row * 256 + (colb ^ ((row & 7) << 4))) = v;
  }
  __syncthreads();

  v4f acc[23];
  v4f z4 = {0.f, 0.f, 0.f, 0.f};
#pragma unroll
  for (int q = 0; q < 23; q++) acc[q] = z4;
#pragma unroll
  for (int kk = 0; kk < 4; kk++) {
    int bir = kk * 64 + lg * 16;
    int ar = wm * 16 + c;
    v8s a = *(v8s*)(sm + ar * 256 + (bir ^ ((ar & 7) << 4)));
#pragma unroll
    for (int q = 0; q < 23; q++) {
      int n = q * 16 + c;
      v8s b = *(v8s*)(sm + 16384 + n * 256 + (bir ^ ((n & 7) << 4)));
      acc[q] = MFMA_B16(a, b, acc[q]);
    }
  }
  float bq[23];
#pragma unroll
  for (int q = 0; q < 23; q++) bq[q] = bpp[q * 16 + c];

  float tp = 0.f, tv = 0.f, ta = 0.f, tn = 0.f;
#pragma unroll
  for (int j = 0; j < 4; j++) {
    int rloc = lg * 4 + j;
    int r = r0 + wm * 16 + rloc;
    int t = r >> 7, b = r & 127;
    int mv = moves[(size_t)b * NT + t];
    float val = values[(size_t)b * NT + t];
    float msk = (val != -9.0f) ? 1.f : 0.f;

    float pmax = -3.0e38f;
#pragma unroll
    for (int q = 0; q < 23; q++) pmax = fmaxf(pmax, acc[q][j] + bq[q]);
#pragma unroll
    for (int d = 1; d < 16; d <<= 1) pmax = fmaxf(pmax, __shfl_xor(pmax, d, 64));
    float ps = 0.f;
#pragma unroll
    for (int q = 0; q < 23; q++) ps += __expf((acc[q][j] + bq[q]) - pmax);
#pragma unroll
    for (int d = 1; d < 16; d <<= 1) ps += __shfl_xor(ps, d, 64);
    float lse = pmax + __logf(ps);

    int qm = mv >> 4, cm = mv & 15;
    float mlv = 0.f;
#pragma unroll
    for (int q = 0; q < 23; q++) if (q == qm) mlv = acc[q][j] + bq[q];
    mlv = __shfl(mlv, (l & 48) + cm, 64);
    float xent = lse - mlv;

    float amx = -3.0e38f; int aix = 0;
#pragma unroll
    for (int q = 0; q < 23; q++) {
      float v = acc[q][j] + bq[q];
      if (v > amx) { amx = v; aix = q * 16 + c; }
    }
#pragma unroll
    for (int d = 1; d < 16; d <<= 1) {
      float ov = __shfl_xor(amx, d, 64);
      int oi = __shfl_xor(aix, d, 64);
      if (ov > amx || (ov == amx && oi < aix)) { amx = ov; aix = oi; }
    }

    float pd = 0.f;
    int vrow = wm * 16 + rloc;
#pragma unroll
    for (int i = 0; i < 8; i++) {
      int k = c * 8 + i;
      short hv = *(short*)(sm + vrow * 256 + ((k * 2) ^ ((vrow & 7) << 4)));
      pd += b2f((unsigned short)hv) * Wv[k];
    }
#pragma unroll
    for (int d = 1; d < 16; d <<= 1) pd += __shfl_xor(pd, d, 64);
    float eo = __expf(2.f * (pd + bv[0]));
    float win = (eo - 1.f) * __builtin_amdgcn_rcpf(eo + 1.f);
    float dv = win - val;

    if (c == 0) {
      tp += msk * xent;
      tv += msk * dv * dv;
      ta += (aix == mv) ? 1.f : 0.f;
      tn += msk;
    }
  }
  tp += __shfl_xor(tp, 16, 64); tp += __shfl_xor(tp, 32, 64);
  tv += __shfl_xor(tv, 16, 64); tv += __shfl_xor(tv, 32, 64);
  ta += __shfl_xor(ta, 16, 64); ta += __shfl_xor(ta, 32, 64);
  tn += __shfl_xor(tn, 16, 64); tn += __shfl_xor(tn, 32, 64);
  if (l == 0) {
    atomicAdd(accum + 0, tp);
    atomicAdd(accum + 1, tv);
    atomicAdd(accum + 2, ta);
    atomicAdd(accum + 3, tn);
  }
  __syncthreads();                           // drains the atomics (vmcnt 0)
  if (tid == 0) {
    int old = __hip_atomic_fetch_add((int*)(accum + 4), 1,
                                     __ATOMIC_ACQ_REL, AG);
    if (old == 1023) {                       // last WG finalizes
      float a0 = __hip_atomic_load(accum + 0, __ATOMIC_RELAXED, AG);
      float a1 = __hip_atomic_load(accum + 1, __ATOMIC_RELAXED, AG);
      float a2 = __hip_atomic_load(accum + 2, __ATOMIC_RELAXED, AG);
      float a3 = __hip_atomic_load(accum + 3, __ATOMIC_RELAXED, AG);
      out[0] = a0 / a3;
      out[1] = a1 / a3;
      out[2] = a2 / 65536.0f;
    }
  }
}

// --------------------------------------------------------------------------
extern "C" void kernel_launch(void* const* d_in, const int* in_sizes, int n_in,
                              void* d_out, int out_size, void* d_ws, size_t ws_size,
                              hipStream_t stream) {
  (void)in_sizes; (void)n_in; (void)out_size; (void)ws_size;
  const float* states = (const float*)d_in[0];
  const int*   moves  = (const int*)d_in[1];
  const float* values = (const float*)d_in[2];
  const float* W0 = (const float*)d_in[3];
  const float* b0 = (const float*)d_in[4];
  const float* W1 = (const float*)d_in[5];
  const float* b1 = (const float*)d_in[6];
  const float* Wp = (const float*)d_in[7];
  const float* bp = (const float*)d_in[8];
  const float* Wv = (const float*)d_in[9];
  const float* bv = (const float*)d_in[10];
  char* ws = (char*)d_ws;

  __hip_bfloat16* zbuf = (__hip_bfloat16*)(ws + OFF_Z);
  __hip_bfloat16* h1   = (__hip_bfloat16*)(ws + OFF_H1);
  __hip_bfloat16* W0xT = (__hip_bfloat16*)(ws + OFF_W0XT);
  __hip_bfloat16* WpT  = (__hip_bfloat16*)(ws + OFF_WPT);
  float* b0p = (float*)(ws + OFF_B0P);
  float* bpp = (float*)(ws + OFF_BPP);
  float* acc = (float*)(ws + OFF_ACC);

  k_conv_weights<<<956, 256, 0, stream>>>(W0, b0, Wp, bp, ws);
  k_gemm2<<<512, 512, 0, stream>>>(states, W0xT, b0p, zbuf);
  k_scan12<<<32, 1024, 0, stream>>>(zbuf, W0, W1, b1, h1);
  k_heads<<<1024, 256, 0, stream>>>(h1, WpT, bpp, Wv, bv, moves, values, acc,
                                    (float*)d_out);
}

// Round 16
// 811.669 us; speedup vs baseline: 1.0219x; 1.0219x over previous
//
#include <hip/hip_runtime.h>
#include <hip/hip_bf16.h>
#include <stdint.h>

// ---------------------------------------------------------------------------
// RNN_79164837199890: 2-layer LSTM (B=128,T=512,H=128) + policy/value heads.
// R16: R14 verbatim EXCEPT the scan's fp8 ring swizzle moves from 8B-slots
// to 16B-slots: AFRAG = 2x ds_read_b128 (was 4x ds_read_b64) -> DS-pipe pool
// per CU-step halves (96->48 reads). byte = R*128 + (((K>>4)^(R&7))<<4)+(K&15)
// on BOTH write and read sides (rule #21). b128 read pattern: lanes' bank
// quads spread 8-way even = the 1KB/wave b128 floor (optimal).
// ---------------------------------------------------------------------------

typedef short v8s __attribute__((ext_vector_type(8)));   // 8 x bf16 fragment
typedef float v4f __attribute__((ext_vector_type(4)));   // MFMA accumulator
typedef int   v8i __attribute__((ext_vector_type(8)));   // 32 x fp8 fragment
typedef float f4u __attribute__((ext_vector_type(4), aligned(4)));  // unaligned-ok

#define MFMA_B16(a,b,c) __builtin_amdgcn_mfma_f32_16x16x32_bf16((a),(b),(c),0,0,0)
#define MFMA_MX(a,b,c) \
  __builtin_amdgcn_mfma_scale_f32_16x16x128_f8f6f4((a),(b),(c),0,0,0,0x7F7F7F7F,0,0x7F7F7F7F)

#define NT     512
#define FIN    361
#define KP0    384
#define NPC    362
#define NPP    368

// workspace offsets (bytes)
#define OFF_Z    ((size_t)0)          // 65536*512*2 = 67108864 (z0x, gate-packed)
#define OFF_H1   ((size_t)83886080)   // 65536*128*2 = 16777216
#define OFF_W0XT ((size_t)100663296)  // 512*384*2 = 393216
#define OFF_WPT  ((size_t)101187584)  // 368*128*2 = 94208
#define OFF_B0P  ((size_t)101281792)  // 512*4
#define OFF_BPP  ((size_t)101285888)  // 368*4
#define OFF_ACC  ((size_t)101287936)  // 4 floats

static __device__ __forceinline__ short f2b(float f) {
  __hip_bfloat16 h = __float2bfloat16(f);
  union { __hip_bfloat16 h; short s; } cv; cv.h = h; return cv.s;
}
static __device__ __forceinline__ float b2f(unsigned int lo16) {
  union { unsigned u; float f; } cv; cv.u = lo16 << 16; return cv.f;
}
// f32 -> OCP e4m3fn with RNE (one-time weight packs)
static __device__ __forceinline__ unsigned f2e4m3(float f) {
  union { float f; unsigned u; } cv; cv.f = f;
  unsigned s = (cv.u >> 31) << 7;
  float a = fabsf(f);
  a = fminf(a, 448.f);
  unsigned code;
  if (a >= 0.015625f) {
    union { float f; unsigned u; } m; m.f = a;
    unsigned u = m.u + 0x7FFFF + ((m.u >> 20) & 1);
    code = (u >> 20) - 960;
    if (code > 126u) code = 126u;
  } else {
    code = (unsigned)rintf(a * 512.f);
  }
  return s | code;
}
// per-step fp8 encode (R7 path)
static __device__ __forceinline__ unsigned f2e4m3_fast(float f) {
#if __has_builtin(__builtin_amdgcn_cvt_pk_fp8_f32)
  return (unsigned)__builtin_amdgcn_cvt_pk_fp8_f32(f, f, 0, false) & 0xffu;
#else
  return f2e4m3(f);
#endif
}

// Raw barrier with LDS-only drain (global stores/loads keep floating).
static __device__ __forceinline__ void sync_lds() {
  __builtin_amdgcn_sched_barrier(0);
  asm volatile("s_waitcnt lgkmcnt(0)" ::: "memory");
  __builtin_amdgcn_s_barrier();
  __builtin_amdgcn_sched_barrier(0);
}

// --------------------------------------------------------------------------
// K0: weight conversion (R7 exact). col' = m*4+g <-> n = m + 128*g;
// forget-gate +1.0 folded into b0p. Zeroes accum.
// --------------------------------------------------------------------------
__global__ __launch_bounds__(256) void k_conv_weights(
    const float* __restrict__ W0, const float* __restrict__ b0,
    const float* __restrict__ Wp, const float* __restrict__ bp,
    char* __restrict__ ws) {
  int idx = blockIdx.x * 256 + threadIdx.x;
  __hip_bfloat16* W0xT = (__hip_bfloat16*)(ws + OFF_W0XT);
  __hip_bfloat16* WpT  = (__hip_bfloat16*)(ws + OFF_WPT);
  float* b0p = (float*)(ws + OFF_B0P);
  float* bpp = (float*)(ws + OFF_BPP);
  float* acc = (float*)(ws + OFF_ACC);

  if (idx < 196608) {                       // W0xT [512 cols'][384 k]
    int np = idx / 384, k = idx - np * 384;
    int n = (np >> 2) + 128 * (np & 3);
    float v = (k < FIN) ? W0[(size_t)k * 512 + n] : 0.f;
    W0xT[idx] = __float2bfloat16(v);
    return;
  }
  idx -= 196608;
  if (idx < 47104) {                        // WpT [368 p][128 k]
    int p = idx >> 7, k = idx & 127;
    WpT[idx] = __float2bfloat16(p < NPC ? Wp[(size_t)k * NPC + p] : 0.f);
    return;
  }
  idx -= 47104;
  if (idx < 512) {                          // b0p packed, +1.0 on forget gate
    int n = (idx >> 2) + 128 * (idx & 3);
    b0p[idx] = b0[n] + (((idx & 3) == 1) ? 1.0f : 0.0f);
    return;
  }
  idx -= 512;
  if (idx < NPP) { bpp[idx] = (idx < NPC) ? bp[idx] : -1e30f; return; }
  idx -= NPP;
  if (idx < 4) { acc[idx] = 0.f; return; }
}

// --------------------------------------------------------------------------
// K1: C[r, col'] = A[r,:] @ BT[col',:]^T + bias[col'] (R14 exact).
// --------------------------------------------------------------------------
template<int KTOT, bool AF32>
__global__ __launch_bounds__(256) void k_gemm(
    const void* __restrict__ Ap, const __hip_bfloat16* __restrict__ BT,
    const float* __restrict__ bias, __hip_bfloat16* __restrict__ C) {
  __shared__ char sm[65536];                 // A: 2x16KB @0, B: 2x16KB @32768
  const int tid = threadIdx.x;
  const int l = tid & 63, wm = tid >> 6;
  const int c = l & 15, lg = l >> 4;
  const int m0 = blockIdx.x * 128;
  const int n0 = blockIdx.y * 128;
  constexpr int NS = KTOT / 64;

  uint4 ra[4], rb[4];
  float fa[32];

  auto LD = [&](int ks) {
#pragma unroll
    for (int i = 0; i < 4; i++) {
      int idx = i * 4096 + tid * 16;
      int row = idx >> 7, colb = idx & 127;
      if constexpr (AF32) {
        int r = m0 + row;
        const float* src = (const float*)Ap + ((size_t)(r & 127) * NT + (r >> 7)) * FIN;
        int kb = ks * 64 + (colb >> 1);
        if (kb + 8 <= FIN) {
          f4u a0 = *(const f4u*)(src + kb);
          f4u a1 = *(const f4u*)(src + kb + 4);
#pragma unroll
          for (int u = 0; u < 4; u++) { fa[i * 8 + u] = a0[u]; fa[i * 8 + 4 + u] = a1[u]; }
        } else {
#pragma unroll
          for (int u = 0; u < 8; u++) {
            int kf = kb + u;
            fa[i * 8 + u] = (kf < FIN) ? src[kf] : 0.f;
          }
        }
      } else {
        ra[i] = *(const uint4*)((const char*)Ap + ((size_t)(m0 + row) * KTOT + ks * 64) * 2 + colb);
      }
      rb[i] = *(const uint4*)((const char*)BT + ((size_t)(n0 + row) * KTOT + ks * 64) * 2 + colb);
    }
  };
  auto ST = [&](int bsel) {
#pragma unroll
    for (int i = 0; i < 4; i++) {
      int idx = i * 4096 + tid * 16;
      int row = idx >> 7, colb = idx & 127;
      int sw = colb ^ ((row & 7) << 4);
      if constexpr (AF32) {
        v8s w;
#pragma unroll
        for (int u = 0; u < 8; u++) w[u] = f2b(fa[i * 8 + u]);
        *(v8s*)(sm + bsel * 16384 + row * 128 + sw) = w;
      } else {
        *(uint4*)(sm + bsel * 16384 + row * 128 + sw) = ra[i];
      }
      *(uint4*)(sm + 32768 + bsel * 16384 + row * 128 + sw) = rb[i];
    }
  };

  v4f acc[2][8];
  v4f z4 = {0.f, 0.f, 0.f, 0.f};
#pragma unroll
  for (int mt = 0; mt < 2; mt++)
#pragma unroll
    for (int nt = 0; nt < 8; nt++) acc[mt][nt] = z4;

  LD(0); ST(0);
  __syncthreads();
  for (int ks = 0; ks < NS; ks++) {
    if (ks + 1 < NS) LD(ks + 1);
    const int bsel = ks & 1;
#pragma unroll
    for (int kk = 0; kk < 2; kk++) {
      int bir = kk * 64 + lg * 16;
      v8s af[2];
#pragma unroll
      for (int mt = 0; mt < 2; mt++) {
        int row = wm * 32 + mt * 16 + c;
        af[mt] = *(v8s*)(sm + bsel * 16384 + row * 128 + (bir ^ ((row & 7) << 4)));
      }
#pragma unroll
      for (int nt = 0; nt < 8; nt++) {
        int n = nt * 16 + c;
        v8s bf = *(v8s*)(sm + 32768 + bsel * 16384 + n * 128 + (bir ^ ((n & 7) << 4)));
#pragma unroll
        for (int mt = 0; mt < 2; mt++) acc[mt][nt] = MFMA_B16(af[mt], bf, acc[mt][nt]);
      }
    }
    if (ks + 1 < NS) ST((ks + 1) & 1);
    __syncthreads();
  }

#pragma unroll
  for (int mt = 0; mt < 2; mt++)
#pragma unroll
    for (int nt = 0; nt < 8; nt++) {
      int colp = n0 + nt * 16 + c;
      float bs = bias[colp];
#pragma unroll
      for (int j = 0; j < 4; j++) {
        int row = m0 + wm * 32 + mt * 16 + lg * 4 + j;
        C[(size_t)row * 512 + colp] = __float2bfloat16(acc[mt][nt][j] + bs);
      }
    }
}

// --------------------------------------------------------------------------
// K2: merged 2-layer scan. R7 structure; fp8 rings use 16B-slot swizzle:
// byte(R,K) = R*128 + (((K>>4)^(R&7))<<4) + (K&15). AFRAG = 2x ds_read_b128.
// 32 WGs x 16 waves. role = wv>>3; lane: m=16rw+c, batch B0+lg (M-row 4lg).
// LDS: h0 fp8 dbuf @0 (2x2KB), h1 fp8 dbuf @4096 (2x2KB).
// --------------------------------------------------------------------------
__global__ __launch_bounds__(1024, 4) void k_scan12(
    const __hip_bfloat16* __restrict__ Z, const float* __restrict__ W0f,
    const float* __restrict__ W1f, const float* __restrict__ b1,
    __hip_bfloat16* __restrict__ h1out) {
  __shared__ char sm[8192];
  const int tid = threadIdx.x;
  const int l = tid & 63, wv = tid >> 6;
  const int c = l & 15, lg = l >> 4;
  const int role = wv >> 3, rw = wv & 7;
  const int B0 = blockIdx.x * 4;
  const int m_ = 16 * rw + c;
  const int row = 4 * lg;                    // M-row this lane's cell lives at
  // 16B-slot swizzled write offset: R=row, K=m_
  const int wf8 = row * 128 + ((((m_ >> 4) ^ row) & 7) << 4) + (m_ & 15);

  for (int e = tid * 4; e < 8192; e += 1024 * 4) *(int*)(sm + e) = 0;

  // A-frag: row c, k = lg*32..lg*32+31 -> slots {2lg, 2lg+1} swizzled by c&7
  auto AFRAG = [&](int base) -> v8i {
    union { uint4 q4[2]; v8i v; } u;
    u.q4[0] = *(const uint4*)(sm + base + c * 128 + ((((2 * lg) ^ c) & 7) << 4));
    u.q4[1] = *(const uint4*)(sm + base + c * 128 + ((((2 * lg + 1) ^ c) & 7) << 4));
    return u.v;
  };

  if (role == 0) {
    // ================= L0 =================
    v8i breg[4];                             // fp8 W0h B-frags
#pragma unroll
    for (int g = 0; g < 4; g++) {
      int n = g * 128 + m_;
      union { unsigned long long q[4]; v8i v; } u;
#pragma unroll
      for (int t = 0; t < 4; t++) {
        unsigned long long w = 0ull;
#pragma unroll
        for (int j = 0; j < 8; j++) {
          int k = lg * 32 + t * 8 + j;
          w |= (unsigned long long)f2e4m3(W0f[(size_t)(FIN + k) * 512 + n]) << (8 * j);
        }
        u.q[t] = w;
      }
      breg[g] = u.v;
    }

    uint2 zA, zB, zC;
    auto ZLD = [&](int t) -> uint2 {
      return *(const uint2*)(Z + ((size_t)t * 128 + B0 + lg) * 512 + m_ * 4);
    };
    zA = ZLD(0); zB = ZLD(1);
    float cst = 0.f;
    __syncthreads();

    for (int s = 0; s < NT; s++) {
      v8i av = AFRAG(((s + 1) & 1) * 2048);  // h0(s-1) fp8
      v4f acc[4];
#pragma unroll
      for (int g = 0; g < 4; g++) acc[g] = (v4f){0.f, 0.f, 0.f, 0.f};
#pragma unroll
      for (int g = 0; g < 4; g++) acc[g] = MFMA_MX(av, breg[g], acc[g]);
      if (s + 2 < NT) zC = ZLD(s + 2);

      float xi = acc[0][0] + b2f(zA.x & 0xffffu);
      float xf = acc[1][0] + b2f(zA.x >> 16);          // +1.0 folded into b0p
      float xg = acc[2][0] + b2f(zA.y & 0xffffu);
      float xo = acc[3][0] + b2f(zA.y >> 16);
      float ei = __expf(-xi);
      float ef = __expf(-xf);
      float eg = __expf(2.f * xg);
      float eo = __expf(-xo);
      float cn = cst * __builtin_amdgcn_rcpf(1.f + ef)
               + (eg - 1.f) * __builtin_amdgcn_rcpf((1.f + ei) * (eg + 1.f));
      cst = cn;
      float ec = __expf(2.f * cn);
      float hv = (ec - 1.f) * __builtin_amdgcn_rcpf((1.f + eo) * (ec + 1.f));
      *(unsigned char*)(sm + (s & 1) * 2048 + wf8) = (unsigned char)f2e4m3_fast(hv);
      zA = zB; zB = zC;
      sync_lds();
    }
    sync_lds();                              // L1 tail step
  } else {
    // ================= L1 (one step behind) =================
    v8i bregH[4], bregX[4];                  // fp8 B-frags
#pragma unroll
    for (int g = 0; g < 4; g++) {
      int n = g * 128 + m_;
      union { unsigned long long q[4]; v8i v; } uh, ux;
#pragma unroll
      for (int t = 0; t < 4; t++) {
        unsigned long long wh = 0ull, wx = 0ull;
#pragma unroll
        for (int j = 0; j < 8; j++) {
          int k = lg * 32 + t * 8 + j;
          wh |= (unsigned long long)f2e4m3(W1f[(size_t)(128 + k) * 512 + n]) << (8 * j);
          wx |= (unsigned long long)f2e4m3(W1f[(size_t)k * 512 + n]) << (8 * j);
        }
        uh.q[t] = wh; ux.q[t] = wx;
      }
      bregH[g] = uh.v; bregX[g] = ux.v;
    }
    float bq[4];
#pragma unroll
    for (int g = 0; g < 4; g++)
      bq[g] = b1[g * 128 + m_] + ((g == 1) ? 1.0f : 0.0f);
    float cst = 0.f;
    __syncthreads();
    sync_lds();                              // skip s=0 (idle)

    for (int s = 1; s <= NT; s++) {
      v8i ah = AFRAG(4096 + (s & 1) * 2048); // h1(s-2) fp8
      v8i ax = AFRAG(((s + 1) & 1) * 2048);  // h0(s-1) fp8
      v4f acc[4];
#pragma unroll
      for (int g = 0; g < 4; g++) acc[g] = (v4f){bq[g], bq[g], bq[g], bq[g]};
#pragma unroll
      for (int g = 0; g < 4; g++) acc[g] = MFMA_MX(ah, bregH[g], acc[g]);
#pragma unroll
      for (int g = 0; g < 4; g++) acc[g] = MFMA_MX(ax, bregX[g], acc[g]);

      float xi = acc[0][0], xf = acc[1][0], xg = acc[2][0], xo = acc[3][0];
      float ei = __expf(-xi);
      float ef = __expf(-xf);
      float eg = __expf(2.f * xg);
      float eo = __expf(-xo);
      float cn = cst * __builtin_amdgcn_rcpf(1.f + ef)
               + (eg - 1.f) * __builtin_amdgcn_rcpf((1.f + ei) * (eg + 1.f));
      cst = cn;
      float ec = __expf(2.f * cn);
      float hv = (ec - 1.f) * __builtin_amdgcn_rcpf((1.f + eo) * (ec + 1.f));
      *(unsigned char*)(sm + 4096 + ((s + 1) & 1) * 2048 + wf8) =
          (unsigned char)f2e4m3_fast(hv);
      union { short s; __hip_bfloat16 h; } cv; cv.s = f2b(hv);
      h1out[((size_t)(s - 1) * 128 + B0 + lg) * 128 + m_] = cv.h;
      sync_lds();
    }
  }
}

// --------------------------------------------------------------------------
// K5: heads (R7 exact). WG = 64 rows (4 waves x 16).
// --------------------------------------------------------------------------
__global__ __launch_bounds__(256) void k_heads(
    const __hip_bfloat16* __restrict__ Hh, const __hip_bfloat16* __restrict__ WpT,
    const float* __restrict__ bpp, const float* __restrict__ Wv,
    const float* __restrict__ bv, const int* __restrict__ moves,
    const float* __restrict__ values, float* __restrict__ accum) {
  __shared__ char sm[110592];                // A 16KB @0, B 94208B @16384
  const int tid = threadIdx.x;
  const int l = tid & 63, wm = tid >> 6;
  const int c = l & 15, lg = l >> 4;
  const int r0 = blockIdx.x * 64;

#pragma unroll
  for (int i = 0; i < 4; i++) {
    int idx = i * 4096 + tid * 16;
    int row = idx >> 8, colb = idx & 255;
    uint4 v = *(const uint4*)((const char*)Hh + (size_t)r0 * 256 + idx);
    *(uint4*)(sm + row * 256 + (colb ^ ((row & 7) << 4))) = v;
  }
#pragma unroll
  for (int i = 0; i < 23; i++) {
    int idx = i * 4096 + tid * 16;
    int row = idx >> 8, colb = idx & 255;
    uint4 v = *(const uint4*)((const char*)WpT + idx);
    *(uint4*)(sm + 16384 + row * 256 + (colb ^ ((row & 7) << 4))) = v;
  }
  __syncthreads();

  v4f acc[23];
  v4f z4 = {0.f, 0.f, 0.f, 0.f};
#pragma unroll
  for (int q = 0; q < 23; q++) acc[q] = z4;
#pragma unroll
  for (int kk = 0; kk < 4; kk++) {
    int bir = kk * 64 + lg * 16;
    int ar = wm * 16 + c;
    v8s a = *(v8s*)(sm + ar * 256 + (bir ^ ((ar & 7) << 4)));
#pragma unroll
    for (int q = 0; q < 23; q++) {
      int n = q * 16 + c;
      v8s b = *(v8s*)(sm + 16384 + n * 256 + (bir ^ ((n & 7) << 4)));
      acc[q] = MFMA_B16(a, b, acc[q]);
    }
  }
  float bq[23];
#pragma unroll
  for (int q = 0; q < 23; q++) bq[q] = bpp[q * 16 + c];

  float tp = 0.f, tv = 0.f, ta = 0.f, tn = 0.f;
#pragma unroll
  for (int j = 0; j < 4; j++) {
    int rloc = lg * 4 + j;
    int r = r0 + wm * 16 + rloc;
    int t = r >> 7, b = r & 127;
    int mv = moves[(size_t)b * NT + t];
    float val = values[(size_t)b * NT + t];
    float msk = (val != -9.0f) ? 1.f : 0.f;

    float pmax = -3.0e38f;
#pragma unroll
    for (int q = 0; q < 23; q++) pmax = fmaxf(pmax, acc[q][j] + bq[q]);
#pragma unroll
    for (int d = 1; d < 16; d <<= 1) pmax = fmaxf(pmax, __shfl_xor(pmax, d, 64));
    float ps = 0.f;
#pragma unroll
    for (int q = 0; q < 23; q++) ps += __expf((acc[q][j] + bq[q]) - pmax);
#pragma unroll
    for (int d = 1; d < 16; d <<= 1) ps += __shfl_xor(ps, d, 64);
    float lse = pmax + __logf(ps);

    int qm = mv >> 4, cm = mv & 15;
    float mlv = 0.f;
#pragma unroll
    for (int q = 0; q < 23; q++) if (q == qm) mlv = acc[q][j] + bq[q];
    mlv = __shfl(mlv, (l & 48) + cm, 64);
    float xent = lse - mlv;

    float amx = -3.0e38f; int aix = 0;
#pragma unroll
    for (int q = 0; q < 23; q++) {
      float v = acc[q][j] + bq[q];
      if (v > amx) { amx = v; aix = q * 16 + c; }
    }
#pragma unroll
    for (int d = 1; d < 16; d <<= 1) {
      float ov = __shfl_xor(amx, d, 64);
      int oi = __shfl_xor(aix, d, 64);
      if (ov > amx || (ov == amx && oi < aix)) { amx = ov; aix = oi; }
    }

    float pd = 0.f;
    int vrow = wm * 16 + rloc;
#pragma unroll
    for (int i = 0; i < 8; i++) {
      int k = c * 8 + i;
      short hv = *(short*)(sm + vrow * 256 + ((k * 2) ^ ((vrow & 7) << 4)));
      pd += b2f((unsigned short)hv) * Wv[k];
    }
#pragma unroll
    for (int d = 1; d < 16; d <<= 1) pd += __shfl_xor(pd, d, 64);
    float eo = __expf(2.f * (pd + bv[0]));
    float win = (eo - 1.f) * __builtin_amdgcn_rcpf(eo + 1.f);
    float dv = win - val;

    if (c == 0) {
      tp += msk * xent;
      tv += msk * dv * dv;
      ta += (aix == mv) ? 1.f : 0.f;
      tn += msk;
    }
  }
  tp += __shfl_xor(tp, 16, 64); tp += __shfl_xor(tp, 32, 64);
  tv += __shfl_xor(tv, 16, 64); tv += __shfl_xor(tv, 32, 64);
  ta += __shfl_xor(ta, 16, 64); ta += __shfl_xor(ta, 32, 64);
  tn += __shfl_xor(tn, 16, 64); tn += __shfl_xor(tn, 32, 64);
  if (l == 0) {
    atomicAdd(accum + 0, tp);
    atomicAdd(accum + 1, tv);
    atomicAdd(accum + 2, ta);
    atomicAdd(accum + 3, tn);
  }
}

__global__ void k_final(const float* __restrict__ accum, float* __restrict__ out) {
  if (threadIdx.x == 0) {
    float nm = accum[3];
    out[0] = accum[0] / nm;
    out[1] = accum[1] / nm;
    out[2] = accum[2] / 65536.0f;
  }
}

// --------------------------------------------------------------------------
extern "C" void kernel_launch(void* const* d_in, const int* in_sizes, int n_in,
                              void* d_out, int out_size, void* d_ws, size_t ws_size,
                              hipStream_t stream) {
  (void)in_sizes; (void)n_in; (void)out_size; (void)ws_size;
  const float* states = (const float*)d_in[0];
  const int*   moves  = (const int*)d_in[1];
  const float* values = (const float*)d_in[2];
  const float* W0 = (const float*)d_in[3];
  const float* b0 = (const float*)d_in[4];
  const float* W1 = (const float*)d_in[5];
  const float* b1 = (const float*)d_in[6];
  const float* Wp = (const float*)d_in[7];
  const float* bp = (const float*)d_in[8];
  const float* Wv = (const float*)d_in[9];
  const float* bv = (const float*)d_in[10];
  char* ws = (char*)d_ws;

  __hip_bfloat16* zbuf = (__hip_bfloat16*)(ws + OFF_Z);
  __hip_bfloat16* h1   = (__hip_bfloat16*)(ws + OFF_H1);
  __hip_bfloat16* W0xT = (__hip_bfloat16*)(ws + OFF_W0XT);
  __hip_bfloat16* WpT  = (__hip_bfloat16*)(ws + OFF_WPT);
  float* b0p = (float*)(ws + OFF_B0P);
  float* bpp = (float*)(ws + OFF_BPP);
  float* acc = (float*)(ws + OFF_ACC);

  k_conv_weights<<<956, 256, 0, stream>>>(W0, b0, Wp, bp, ws);
  k_gemm<KP0, true><<<dim3(512, 4), 256, 0, stream>>>(states, W0xT, b0p, zbuf);
  k_scan12<<<32, 1024, 0, stream>>>(zbuf, W0, W1, b1, h1);
  k_heads<<<1024, 256, 0, stream>>>(h1, WpT, bpp, Wv, bv, moves, values, acc);
  k_final<<<1, 1, 0, stream>>>(acc, (float*)d_out);
}